// Round 17
// baseline (258.735 us; speedup 1.0000x reference)
//
#include <hip/hip_runtime.h>
#include <hip/hip_bf16.h>

typedef __bf16 bf16_t;
typedef __bf16 bf16x8 __attribute__((ext_vector_type(8)));
typedef float f32x4 __attribute__((ext_vector_type(4)));
typedef float f32x16 __attribute__((ext_vector_type(16)));

#define SEQ_L 8192
#define DMODEL 1024
#define NHEAD 16
#define HDIM 64
static constexpr int MROWS = 2 * SEQ_L;  // B*L = 16384

// ---------------- async global->LDS (16B per lane) ----------------
__device__ __forceinline__ void async_cp16(const void* g, bf16_t* l) {
  __builtin_amdgcn_global_load_lds(
      (__attribute__((address_space(1))) void*)(void*)(g),
      (__attribute__((address_space(3))) void*)(void*)(l), 16, 0, 0);
}
// Raw barrier: does NOT drain vmcnt/lgkmcnt (waits are placed by hand).
__device__ __forceinline__ void wg_barrier() { __builtin_amdgcn_s_barrier(); }

// ------------- merged preamble: convert + weight-transpose + rope -------------
// blocks [0,8192):        f32->bf16 convert of x (256 thr x 8 elems)
// blocks [8192,12288):    W (KxN f32) -> Wt (NxK bf16), 32x32 tiles, 4 weights
// blocks [12288,13312):   RoPE cos/sin table tab[pos*32+j]
__global__ __launch_bounds__(256) void prep_k(
    const float* __restrict__ x, bf16_t* __restrict__ xb,
    const float* __restrict__ W0, const float* __restrict__ W1,
    const float* __restrict__ W2, const float* __restrict__ W3,
    bf16_t* __restrict__ T0, bf16_t* __restrict__ T1,
    bf16_t* __restrict__ T2, bf16_t* __restrict__ T3,
    float2* __restrict__ tab) {
  __shared__ float tile[32][33];
  const int bid = blockIdx.x;
  const int tid = threadIdx.x;
  if (bid < 8192) {
    const int i = (bid * 256 + tid) * 8;
    float4 a = *(const float4*)(x + i);
    float4 b = *(const float4*)(x + i + 4);
    bf16x8 o;
    o[0] = (__bf16)a.x; o[1] = (__bf16)a.y; o[2] = (__bf16)a.z; o[3] = (__bf16)a.w;
    o[4] = (__bf16)b.x; o[5] = (__bf16)b.y; o[6] = (__bf16)b.z; o[7] = (__bf16)b.w;
    *(bf16x8*)(xb + i) = o;
  } else if (bid < 12288) {
    const int id2 = bid - 8192;
    const int z = id2 >> 10;
    const int by = (id2 & 1023) >> 5;
    const int bx = id2 & 31;
    const float* W = (z == 0) ? W0 : (z == 1) ? W1 : (z == 2) ? W2 : W3;
    bf16_t* T = (z == 0) ? T0 : (z == 1) ? T1 : (z == 2) ? T2 : T3;
    const int tx = tid & 31, ty = tid >> 5;  // 32 x 8
#pragma unroll
    for (int r = 0; r < 4; ++r)
      tile[ty + r * 8][tx] = W[(size_t)(by * 32 + ty + r * 8) * DMODEL + bx * 32 + tx];
    __syncthreads();
#pragma unroll
    for (int r = 0; r < 4; ++r)
      T[(size_t)(bx * 32 + ty + r * 8) * DMODEL + by * 32 + tx] = (bf16_t)tile[tx][ty + r * 8];
  } else {
    const int i = (bid - 12288) * 256 + tid;  // pos*32 + j
    const int pos = i >> 5, j = i & 31;
    double freq = pow(10000.0, -(double)j / 32.0);
    double ang = (double)pos * freq;
    tab[i] = make_float2((float)cos(ang), (float)sin(ang));
  }
}

// -- 256x128 GEMM, 32x32x16 MFMA, 128x64/wave, BK=64 single-buffer (R17) --
// C(M x N) = A(M x K) @ Bt(N x K)^T + bias.  4 waves (2M x 2N); per wave
// 4x2 tiles of 32x32 (acc[4][2] f32x16 = 128 AGPR).  Rationale: QKV at R14/16
// ran at 2552 cyc/CU/K-tile = 97% of the 16x16-rate MFMA-issue floor (2483);
// the 32x32x16 rate (2382 TF, m06) drops the issue floor to ~2065, leaving
// LDS reads (24 ds_read_b128/wave/tile, ~2304 cyc/CU) as the new bound.
// Fragment maps (m74/m101): A/B lane l -> row l&31, k = (l>>5)*8 + j;
// C/D: col = lane&31, row = (reg&3) + 8*(reg>>2) + 4*(lane>>5).
// K-tile boundary, staging and the measured-0-conflict swizzle (physical
// chunk = logical ^ (row&7), source pre-swizzled, LDS dest linear) are
// identical to R16.  RoPE partner d+-32 = other n-tile, same lane/reg.
// MODE 0: fused QKV (N=3072), bias per range, RoPE on q/k, bf16 outs (stride 1024).
// MODE 1: f32 out + bias (O projection, N=1024).
template <int MODE>
__global__ __launch_bounds__(256, 2) void gemm256x128(
    const bf16_t* __restrict__ A, const bf16_t* __restrict__ Bt,
    const float* __restrict__ b0, const float* __restrict__ b1,
    const float* __restrict__ b2, const float2* __restrict__ rope,
    void* __restrict__ O0, void* __restrict__ O1, void* __restrict__ O2) {
  constexpr int K = DMODEL;   // 1024
  constexpr int KT = K / 64;  // 16 K-tiles (BK=64)
  __shared__ bf16_t As_[256 * 64];  // 32 KB
  __shared__ bf16_t Bs_[128 * 64];  // 16 KB
  const int tid = threadIdx.x;
  const int lane = tid & 63;
  const int wave = tid >> 6;  // 0..3
  const int wm = wave >> 1;   // 0..1 (128-row half)
  const int wn = wave & 1;    // 0..1 (64-col half)
  const size_t row0 = (size_t)blockIdx.x * 256;
  const int col0 = blockIdx.y * 128;
  const int l31 = lane & 31;
  const int hk = lane >> 5;  // 0..1: k-subchunk within a 16-wide K-step

  // staging: identical to R16 (thread rows (tid>>3)+32c, chunk tid&7 pre-swz)
  const int srow = tid >> 3;
  const int sch = (tid & 7) ^ ((tid >> 3) & 7);
  const bf16_t* gA = A + (row0 + srow) * K + sch * 8;
  const bf16_t* gB = Bt + ((size_t)col0 + srow) * K + sch * 8;

#define VMCNT(n) asm volatile("s_waitcnt vmcnt(" #n ")")
#define LGKM0() asm volatile("s_waitcnt lgkmcnt(0)")
#define SCHED_FENCE() __builtin_amdgcn_sched_barrier(0)

  auto stage = [&](int j) {
#pragma unroll
    for (int c = 0; c < 8; ++c)  // A: 256 rows
      async_cp16(gA + (size_t)(32 * c) * K + j * 64, As_ + c * 2048 + tid * 8);
#pragma unroll
    for (int c = 0; c < 4; ++c)  // B: 128 rows
      async_cp16(gB + (size_t)(32 * c) * K + j * 64, Bs_ + c * 2048 + tid * 8);
  };
  // fragment read for K-step s (0..3): chunk = s*2 + hk, row per 32x32 tile
  auto read_a = [&](int mt, int s) -> bf16x8 {
    const int R = wm * 128 + mt * 32 + l31;
    return *(const bf16x8*)((const char*)As_ + (size_t)R * 128 +
                            (((s * 2 + hk) ^ (R & 7)) << 4));
  };
  auto read_b = [&](int nt, int s) -> bf16x8 {
    const int R = wn * 64 + nt * 32 + l31;
    return *(const bf16x8*)((const char*)Bs_ + (size_t)R * 128 +
                            (((s * 2 + hk) ^ (R & 7)) << 4));
  };

  f32x16 acc[4][2] = {};
  bf16x8 af[4], bfr[2];

  // prologue
  stage(0);
  VMCNT(0);
  wg_barrier();
  SCHED_FENCE();

  for (int m = 0; m < KT; ++m) {
#pragma unroll
    for (int s = 0; s < 4; ++s) {
#pragma unroll
      for (int mt = 0; mt < 4; ++mt) af[mt] = read_a(mt, s);
#pragma unroll
      for (int nt = 0; nt < 2; ++nt) bfr[nt] = read_b(nt, s);
      __builtin_amdgcn_s_setprio(1);
#pragma unroll
      for (int mt = 0; mt < 4; ++mt)
#pragma unroll
        for (int nt = 0; nt < 2; ++nt)
          acc[mt][nt] = __builtin_amdgcn_mfma_f32_32x32x16_bf16(af[mt], bfr[nt], acc[mt][nt], 0, 0, 0);
      __builtin_amdgcn_s_setprio(0);
    }
    // ---- tile boundary (R16) ----
    LGKM0();
    SCHED_FENCE();
    wg_barrier();
    SCHED_FENCE();
    if (m + 1 < KT) stage(m + 1);
    VMCNT(0);
    wg_barrier();
    SCHED_FENCE();
  }
#undef VMCNT
#undef LGKM0
#undef SCHED_FENCE

  // ---- epilogue. C/D: col = lane&31, row = (r&3) + 8*(r>>2) + 4*hk ----
  const int gcol = col0 + wn * 64;  // head-aligned
  int which = 0;
  const float* bias = b0;
  int obase = gcol;
  if constexpr (MODE == 0) {
    which = gcol >> 10;
    bias = (which == 0) ? b0 : (which == 1) ? b1 : b2;
    obase = gcol - (which << 10);
  }
  const bool do_rope = (MODE == 0) && (which < 2);
  bf16_t* Cb = nullptr;
  float* Cf = nullptr;
  if constexpr (MODE == 0)
    Cb = (bf16_t*)((which == 0) ? O0 : (which == 1) ? O1 : O2);
  else
    Cf = (float*)O0;

  const float bias0 = bias[obase + l31];
  const float bias1 = bias[obase + 32 + l31];

#pragma unroll
  for (int mt = 0; mt < 4; ++mt) {
#pragma unroll
    for (int r = 0; r < 16; ++r) {
      const size_t grow = row0 + wm * 128 + mt * 32 + (r & 3) + 8 * (r >> 2) + 4 * hk;
      float v0 = acc[mt][0][r] + bias0;  // in-head d = l31       (nt=0)
      float v1 = acc[mt][1][r] + bias1;  // in-head d = 32 + l31  (nt=1)
      if (do_rope) {
        const int pos = (int)(grow & (size_t)(SEQ_L - 1));
        const float2* rp = rope + (size_t)pos * 32;
        const float2 cs0 = rp[l31 >> 1];         // j for d = l31
        const float2 cs1 = rp[16 + (l31 >> 1)];  // j for d = 32 + l31
        const float r0 = v0 * cs0.x - v1 * cs0.y;
        const float r1 = v1 * cs1.x + v0 * cs1.y;
        v0 = r0; v1 = r1;
      }
      const size_t cbase = grow * (size_t)DMODEL + obase + l31;
      if constexpr (MODE == 1) {
        Cf[cbase] = v0;
        Cf[cbase + 32] = v1;
      } else {
        Cb[cbase] = (bf16_t)v0;
        Cb[cbase + 32] = (bf16_t)v1;
      }
    }
  }
}

// ---------------- per-position head-mixing attention ----------------
__global__ __launch_bounds__(256) void attn_heads_k(const bf16_t* __restrict__ qb,
                                                    const bf16_t* __restrict__ kb,
                                                    const bf16_t* __restrict__ vb,
                                                    bf16_t* __restrict__ ob) {
  const int t = blockIdx.x * 256 + threadIdx.x;
  const int row = t >> 4;
  const int h = t & 15;
  const size_t rbase = (size_t)row * DMODEL;

  float q[HDIM];
#pragma unroll
  for (int j = 0; j < 8; ++j) {
    bf16x8 v8 = *(const bf16x8*)(qb + rbase + h * HDIM + j * 8);
#pragma unroll
    for (int u = 0; u < 8; ++u) q[j * 8 + u] = (float)v8[u];
  }
  float s[NHEAD];
#pragma unroll
  for (int e = 0; e < NHEAD; ++e) {
    float a = 0.f;
#pragma unroll
    for (int j = 0; j < 8; ++j) {
      bf16x8 k8 = *(const bf16x8*)(kb + rbase + e * HDIM + j * 8);
#pragma unroll
      for (int u = 0; u < 8; ++u) a += q[j * 8 + u] * (float)k8[u];
    }
    s[e] = a * 0.125f;
  }
  float mx = s[0];
#pragma unroll
  for (int e = 1; e < NHEAD; ++e) mx = fmaxf(mx, s[e]);
  float sum = 0.f;
#pragma unroll
  for (int e = 0; e < NHEAD; ++e) {
    s[e] = __expf(s[e] - mx);
    sum += s[e];
  }
  const float inv = 1.f / sum;
  float o[HDIM] = {};
#pragma unroll
  for (int e = 0; e < NHEAD; ++e) {
    const float w = s[e] * inv;
#pragma unroll
    for (int j = 0; j < 8; ++j) {
      bf16x8 v8 = *(const bf16x8*)(vb + rbase + e * HDIM + j * 8);
#pragma unroll
      for (int u = 0; u < 8; ++u) o[j * 8 + u] += w * (float)v8[u];
    }
  }
#pragma unroll
  for (int j = 0; j < 8; ++j) {
    bf16x8 st;
#pragma unroll
    for (int u = 0; u < 8; ++u) st[u] = (__bf16)o[j * 8 + u];
    *(bf16x8*)(ob + rbase + h * HDIM + j * 8) = st;
  }
}

extern "C" void kernel_launch(void* const* d_in, const int* in_sizes, int n_in,
                              void* d_out, int out_size, void* d_ws, size_t ws_size,
                              hipStream_t stream) {
  const float* x = (const float*)d_in[0];
  const float* Wq = (const float*)d_in[1];
  const float* bq = (const float*)d_in[2];
  const float* Wk = (const float*)d_in[3];
  const float* bk = (const float*)d_in[4];
  const float* Wv = (const float*)d_in[5];
  const float* bv = (const float*)d_in[6];
  const float* Wo = (const float*)d_in[7];
  const float* bo = (const float*)d_in[8];

  const int M = MROWS, N = DMODEL, K = DMODEL;

  char* p = (char*)d_ws;
  bf16_t* xb = (bf16_t*)p;    p += (size_t)M * K * 2;      // 32 MB
  bf16_t* Wqkvt = (bf16_t*)p; p += (size_t)3 * N * K * 2;  // 6 MB (q|k|v rows)
  bf16_t* Wot = (bf16_t*)p;   p += (size_t)N * K * 2;      // 2 MB
  bf16_t* qb = (bf16_t*)p;    p += (size_t)M * N * 2;      // 32 MB each
  bf16_t* kb = (bf16_t*)p;    p += (size_t)M * N * 2;
  bf16_t* vb = (bf16_t*)p;    p += (size_t)M * N * 2;
  bf16_t* ab = (bf16_t*)p;    p += (size_t)M * N * 2;
  float2* rope = (float2*)p;  p += (size_t)SEQ_L * 32 * sizeof(float2);  // 2 MB

  bf16_t* Wqt = Wqkvt;
  bf16_t* Wkt = Wqkvt + (size_t)N * K;
  bf16_t* Wvt = Wqkvt + (size_t)2 * N * K;

  // merged preamble: convert (8192) + w-transpose (4096) + rope (1024)
  prep_k<<<13312, 256, 0, stream>>>(x, xb, Wq, Wk, Wv, Wo, Wqt, Wkt, Wvt, Wot, rope);

  // fused QKV: C(16384 x 3072), 64 x 24 blocks of 256x128
  gemm256x128<0><<<dim3(M / 256, (3 * N) / 128), 256, 0, stream>>>(
      xb, Wqkvt, bq, bk, bv, rope, (void*)qb, (void*)kb, (void*)vb);
  attn_heads_k<<<(M * NHEAD) / 256, 256, 0, stream>>>(qb, kb, vb, ab);
  gemm256x128<1><<<dim3(M / 256, N / 128), 256, 0, stream>>>(
      ab, Wot, bo, nullptr, nullptr, nullptr, d_out, nullptr, nullptr);
}

// Round 18
// 223.423 us; speedup vs baseline: 1.1580x; 1.1580x over previous
//
#include <hip/hip_runtime.h>
#include <hip/hip_bf16.h>

typedef __bf16 bf16_t;
typedef __bf16 bf16x8 __attribute__((ext_vector_type(8)));
typedef float f32x4 __attribute__((ext_vector_type(4)));

#define SEQ_L 8192
#define DMODEL 1024
#define NHEAD 16
#define HDIM 64
static constexpr int MROWS = 2 * SEQ_L;  // B*L = 16384

// ---------------- async global->LDS (16B per lane) ----------------
__device__ __forceinline__ void async_cp16(const void* g, bf16_t* l) {
  __builtin_amdgcn_global_load_lds(
      (__attribute__((address_space(1))) void*)(void*)(g),
      (__attribute__((address_space(3))) void*)(void*)(l), 16, 0, 0);
}
// Raw barrier: does NOT drain vmcnt/lgkmcnt (waits are placed by hand).
__device__ __forceinline__ void wg_barrier() { __builtin_amdgcn_s_barrier(); }

// ------------- merged preamble: convert + weight-transpose + rope -------------
// blocks [0,8192):        f32->bf16 convert of x (256 thr x 8 elems)
// blocks [8192,12288):    W (KxN f32) -> Wt (NxK bf16), 32x32 tiles, 4 weights
// blocks [12288,13312):   RoPE cos/sin table tab[pos*32+j]
__global__ __launch_bounds__(256) void prep_k(
    const float* __restrict__ x, bf16_t* __restrict__ xb,
    const float* __restrict__ W0, const float* __restrict__ W1,
    const float* __restrict__ W2, const float* __restrict__ W3,
    bf16_t* __restrict__ T0, bf16_t* __restrict__ T1,
    bf16_t* __restrict__ T2, bf16_t* __restrict__ T3,
    float2* __restrict__ tab) {
  __shared__ float tile[32][33];
  const int bid = blockIdx.x;
  const int tid = threadIdx.x;
  if (bid < 8192) {
    const int i = (bid * 256 + tid) * 8;
    float4 a = *(const float4*)(x + i);
    float4 b = *(const float4*)(x + i + 4);
    bf16x8 o;
    o[0] = (__bf16)a.x; o[1] = (__bf16)a.y; o[2] = (__bf16)a.z; o[3] = (__bf16)a.w;
    o[4] = (__bf16)b.x; o[5] = (__bf16)b.y; o[6] = (__bf16)b.z; o[7] = (__bf16)b.w;
    *(bf16x8*)(xb + i) = o;
  } else if (bid < 12288) {
    const int id2 = bid - 8192;
    const int z = id2 >> 10;
    const int by = (id2 & 1023) >> 5;
    const int bx = id2 & 31;
    const float* W = (z == 0) ? W0 : (z == 1) ? W1 : (z == 2) ? W2 : W3;
    bf16_t* T = (z == 0) ? T0 : (z == 1) ? T1 : (z == 2) ? T2 : T3;
    const int tx = tid & 31, ty = tid >> 5;  // 32 x 8
#pragma unroll
    for (int r = 0; r < 4; ++r)
      tile[ty + r * 8][tx] = W[(size_t)(by * 32 + ty + r * 8) * DMODEL + bx * 32 + tx];
    __syncthreads();
#pragma unroll
    for (int r = 0; r < 4; ++r)
      T[(size_t)(bx * 32 + ty + r * 8) * DMODEL + by * 32 + tx] = (bf16_t)tile[tx][ty + r * 8];
  } else {
    const int i = (bid - 12288) * 256 + tid;  // pos*32 + j
    const int pos = i >> 5, j = i & 31;
    double freq = pow(10000.0, -(double)j / 32.0);
    double ang = (double)pos * freq;
    tab[i] = make_float2((float)cos(ang), (float)sin(ang));
  }
}

// -- 256x128 bf16 GEMM, 128x64 per wave, BK=64 single-buffer, anti-phase --
// Session-best GEMM (885 TF QKV).  This structure sits AT the documented
// plain-HIP 2-barrier-loop ceiling (~900 TF, m103); five structural variants
// (BK=32 dbuf, BK=64 dbuf, 4-phase 256^2, 8-phase 256^2, 32x32-MFMA) all
// measured equal or worse, so it is frozen here.
// Per K-tile: {reads kh0 (12 x ds_read_b128) + 32 MFMA, reads kh1 + 32 MFMA}
// -> lgkm0 -> barrier -> stage(m+1) (12 cp16, WAR-safe) -> vmcnt(0) -> barrier.
// Swizzle (measured 0-conflict with the fr/g4 16x16 fragment pattern ONLY):
// physical 16B chunk = logical ^ (row&7); read applies XOR; write pre-swizzles
// the GLOBAL source chunk, LDS dest linear (global_load_lds requirement).
// MODE 0: fused QKV (N=3072), bias per range, RoPE on q/k, bf16 outs (stride 1024).
// MODE 1: f32 out + bias (O projection, N=1024).
template <int MODE>
__global__ __launch_bounds__(256, 2) void gemm256x128(
    const bf16_t* __restrict__ A, const bf16_t* __restrict__ Bt,
    const float* __restrict__ b0, const float* __restrict__ b1,
    const float* __restrict__ b2, const float2* __restrict__ rope,
    void* __restrict__ O0, void* __restrict__ O1, void* __restrict__ O2) {
  constexpr int K = DMODEL;   // 1024
  constexpr int KT = K / 64;  // 16 K-tiles (BK=64)
  __shared__ bf16_t As_[256 * 64];  // 32 KB
  __shared__ bf16_t Bs_[128 * 64];  // 16 KB
  const int tid = threadIdx.x;
  const int lane = tid & 63;
  const int wave = tid >> 6;  // 0..3
  const int wm = wave >> 1;   // 0..1 (128-row half)
  const int wn = wave & 1;    // 0..1 (64-col half)
  const size_t row0 = (size_t)blockIdx.x * 256;
  const int col0 = blockIdx.y * 128;
  const int fr = lane & 15;
  const int g4 = lane >> 4;  // 0..3: 16B k-chunk group

  // staging: thread covers rows (tid>>3) + 32c, physical chunk tid&7;
  // source chunk pre-swizzled by ((tid>>3)&7) == row&7 for all c (32c%8==0).
  const int srow = tid >> 3;                      // 0..31
  const int sch = (tid & 7) ^ ((tid >> 3) & 7);   // pre-swizzled source chunk
  const bf16_t* gA = A + (row0 + srow) * K + sch * 8;
  const bf16_t* gB = Bt + ((size_t)col0 + srow) * K + sch * 8;

#define VMCNT(n) asm volatile("s_waitcnt vmcnt(" #n ")")
#define LGKM0() asm volatile("s_waitcnt lgkmcnt(0)")
#define SCHED_FENCE() __builtin_amdgcn_sched_barrier(0)

  auto stage = [&](int j) {
#pragma unroll
    for (int c = 0; c < 8; ++c)  // A: 256 rows
      async_cp16(gA + (size_t)(32 * c) * K + j * 64, As_ + c * 2048 + tid * 8);
#pragma unroll
    for (int c = 0; c < 4; ++c)  // B: 128 rows
      async_cp16(gB + (size_t)(32 * c) * K + j * 64, Bs_ + c * 2048 + tid * 8);
  };
  auto read_a = [&](int f, int h) -> bf16x8 {
    const int R = wm * 128 + f * 16 + fr;
    return *(const bf16x8*)((const char*)As_ + (size_t)R * 128 +
                            (((h * 4 + g4) ^ (R & 7)) << 4));
  };
  auto read_b = [&](int n, int h) -> bf16x8 {
    const int R = wn * 64 + n * 16 + fr;
    return *(const bf16x8*)((const char*)Bs_ + (size_t)R * 128 +
                            (((h * 4 + g4) ^ (R & 7)) << 4));
  };

  f32x4 acc[8][4] = {};
  bf16x8 a8[8], b4[4];

  // prologue
  stage(0);
  VMCNT(0);
  wg_barrier();
  SCHED_FENCE();

  for (int m = 0; m < KT; ++m) {
#pragma unroll
    for (int h = 0; h < 2; ++h) {
#pragma unroll
      for (int f = 0; f < 8; ++f) a8[f] = read_a(f, h);
#pragma unroll
      for (int n = 0; n < 4; ++n) b4[n] = read_b(n, h);
      __builtin_amdgcn_s_setprio(1);
#pragma unroll
      for (int f = 0; f < 8; ++f)
#pragma unroll
        for (int n = 0; n < 4; ++n)
          acc[f][n] = __builtin_amdgcn_mfma_f32_16x16x32_bf16(a8[f], b4[n], acc[f][n], 0, 0, 0);
      __builtin_amdgcn_s_setprio(0);
    }
    // ---- tile boundary ----
    LGKM0();
    SCHED_FENCE();
    wg_barrier();  // all waves done reading tile m
    SCHED_FENCE();
    if (m + 1 < KT) stage(m + 1);  // WAR-safe overwrite
    VMCNT(0);                      // new tile landed
    wg_barrier();
    SCHED_FENCE();
  }
#undef VMCNT
#undef LGKM0
#undef SCHED_FENCE

  // ---- epilogue. C/D layout: col = lane&15, row = (lane>>4)*4 + reg ----
  const int lr = g4 * 4;
  const int lc = lane & 15;
  const int gcol = col0 + wn * 64;  // aligned to one head (64)
  int which = 0;
  const float* bias = b0;
  int ocol = gcol;
  if constexpr (MODE == 0) {
    which = gcol >> 10;
    bias = (which == 0) ? b0 : (which == 1) ? b1 : b2;
    ocol = gcol - (which << 10);
  }
  const bool do_rope = (MODE == 0) && (which < 2);
  bf16_t* Cb = nullptr;
  float* Cf = nullptr;
  if constexpr (MODE == 0)
    Cb = (bf16_t*)((which == 0) ? O0 : (which == 1) ? O1 : O2);
  else
    Cf = (float*)O0;

#pragma unroll
  for (int mf = 0; mf < 8; ++mf) {
#pragma unroll
    for (int i = 0; i < 4; ++i) {
      const size_t grow = row0 + wm * 128 + mf * 16 + lr + i;
      float vv[4];
#pragma unroll
      for (int n = 0; n < 4; ++n) vv[n] = acc[mf][n][i] + bias[ocol + n * 16 + lc];
      if (do_rope) {
        // d(in-head) = n*16+lc; j = d>>1; partner d<32 ? d+32 (-sin) : d-32 (+sin)
        const int pos = (int)(grow & (size_t)(SEQ_L - 1));
        const float2* rp = rope + (size_t)pos * 32 + (lc >> 1);
        float rv[4];
#pragma unroll
        for (int n = 0; n < 4; ++n) {
          float2 cs = rp[n * 8];
          rv[n] = (n < 2) ? vv[n] * cs.x - vv[n + 2] * cs.y
                          : vv[n] * cs.x + vv[n - 2] * cs.y;
        }
#pragma unroll
        for (int n = 0; n < 4; ++n) vv[n] = rv[n];
      }
      const size_t cbase = grow * (size_t)DMODEL + ocol + lc;
      if constexpr (MODE == 1) {
#pragma unroll
        for (int n = 0; n < 4; ++n) Cf[cbase + n * 16] = vv[n];
      } else {
#pragma unroll
        for (int n = 0; n < 4; ++n) Cb[cbase + n * 16] = (bf16_t)vv[n];
      }
    }
  }
}

// ---------------- per-position head-mixing attention ----------------
__global__ __launch_bounds__(256) void attn_heads_k(const bf16_t* __restrict__ qb,
                                                    const bf16_t* __restrict__ kb,
                                                    const bf16_t* __restrict__ vb,
                                                    bf16_t* __restrict__ ob) {
  const int t = blockIdx.x * 256 + threadIdx.x;
  const int row = t >> 4;
  const int h = t & 15;
  const size_t rbase = (size_t)row * DMODEL;

  float q[HDIM];
#pragma unroll
  for (int j = 0; j < 8; ++j) {
    bf16x8 v8 = *(const bf16x8*)(qb + rbase + h * HDIM + j * 8);
#pragma unroll
    for (int u = 0; u < 8; ++u) q[j * 8 + u] = (float)v8[u];
  }
  float s[NHEAD];
#pragma unroll
  for (int e = 0; e < NHEAD; ++e) {
    float a = 0.f;
#pragma unroll
    for (int j = 0; j < 8; ++j) {
      bf16x8 k8 = *(const bf16x8*)(kb + rbase + e * HDIM + j * 8);
#pragma unroll
      for (int u = 0; u < 8; ++u) a += q[j * 8 + u] * (float)k8[u];
    }
    s[e] = a * 0.125f;
  }
  float mx = s[0];
#pragma unroll
  for (int e = 1; e < NHEAD; ++e) mx = fmaxf(mx, s[e]);
  float sum = 0.f;
#pragma unroll
  for (int e = 0; e < NHEAD; ++e) {
    s[e] = __expf(s[e] - mx);
    sum += s[e];
  }
  const float inv = 1.f / sum;
  float o[HDIM] = {};
#pragma unroll
  for (int e = 0; e < NHEAD; ++e) {
    const float w = s[e] * inv;
#pragma unroll
    for (int j = 0; j < 8; ++j) {
      bf16x8 v8 = *(const bf16x8*)(vb + rbase + e * HDIM + j * 8);
#pragma unroll
      for (int u = 0; u < 8; ++u) o[j * 8 + u] += w * (float)v8[u];
    }
  }
#pragma unroll
  for (int j = 0; j < 8; ++j) {
    bf16x8 st;
#pragma unroll
    for (int u = 0; u < 8; ++u) st[u] = (__bf16)o[j * 8 + u];
    *(bf16x8*)(ob + rbase + h * HDIM + j * 8) = st;
  }
}

extern "C" void kernel_launch(void* const* d_in, const int* in_sizes, int n_in,
                              void* d_out, int out_size, void* d_ws, size_t ws_size,
                              hipStream_t stream) {
  const float* x = (const float*)d_in[0];
  const float* Wq = (const float*)d_in[1];
  const float* bq = (const float*)d_in[2];
  const float* Wk = (const float*)d_in[3];
  const float* bk = (const float*)d_in[4];
  const float* Wv = (const float*)d_in[5];
  const float* bv = (const float*)d_in[6];
  const float* Wo = (const float*)d_in[7];
  const float* bo = (const float*)d_in[8];

  const int M = MROWS, N = DMODEL, K = DMODEL;

  char* p = (char*)d_ws;
  bf16_t* xb = (bf16_t*)p;    p += (size_t)M * K * 2;      // 32 MB
  bf16_t* Wqkvt = (bf16_t*)p; p += (size_t)3 * N * K * 2;  // 6 MB (q|k|v rows)
  bf16_t* Wot = (bf16_t*)p;   p += (size_t)N * K * 2;      // 2 MB
  bf16_t* qb = (bf16_t*)p;    p += (size_t)M * N * 2;      // 32 MB each
  bf16_t* kb = (bf16_t*)p;    p += (size_t)M * N * 2;
  bf16_t* vb = (bf16_t*)p;    p += (size_t)M * N * 2;
  bf16_t* ab = (bf16_t*)p;    p += (size_t)M * N * 2;
  float2* rope = (float2*)p;  p += (size_t)SEQ_L * 32 * sizeof(float2);  // 2 MB

  bf16_t* Wqt = Wqkvt;
  bf16_t* Wkt = Wqkvt + (size_t)N * K;
  bf16_t* Wvt = Wqkvt + (size_t)2 * N * K;

  // merged preamble: convert (8192) + w-transpose (4096) + rope (1024)
  prep_k<<<13312, 256, 0, stream>>>(x, xb, Wq, Wk, Wv, Wo, Wqt, Wkt, Wvt, Wot, rope);

  // fused QKV: C(16384 x 3072), 64 x 24 blocks of 256x128
  gemm256x128<0><<<dim3(M / 256, (3 * N) / 128), 256, 0, stream>>>(
      xb, Wqkvt, bq, bk, bv, rope, (void*)qb, (void*)kb, (void*)vb);
  attn_heads_k<<<(M * NHEAD) / 256, 256, 0, stream>>>(qb, kb, vb, ab);
  gemm256x128<1><<<dim3(M / 256, N / 128), 256, 0, stream>>>(
      ab, Wot, bo, nullptr, nullptr, nullptr, d_out, nullptr, nullptr);
}